// Round 1
// baseline (101.323 us; speedup 1.0000x reference)
//
#include <hip/hip_runtime.h>

// Problem constants
#define D_MODEL 1024
#define KK 64
#define BSZ 16

// ---------------------------------------------------------------------------
// Kernel A: one wave per row r in [0, BS*K): compute
//   P1[r][c] = sum_d Mp[r,d] * W1[c,d]   (W1 = W[c, 0:1024])
//   P2[r][c] = sum_d Mp[r,d] * W2[c,d]   (W2 = W[c, 1024:2048])
// P12 layout: P1 at [0, 3072), P2 at [3072, 6144) floats.
// ---------------------------------------------------------------------------
__global__ __launch_bounds__(256) void precompute_rows(
    const float* __restrict__ Mp, const float* __restrict__ W,
    float* __restrict__ P12)
{
    const int wave = (blockIdx.x * 256 + threadIdx.x) >> 6;  // 0..1023
    const int lane = threadIdx.x & 63;
    const float* row = Mp + (size_t)wave * D_MODEL;

    float s[6] = {0.f, 0.f, 0.f, 0.f, 0.f, 0.f};
#pragma unroll
    for (int k = 0; k < 4; ++k) {
        const int d = k * 256 + lane * 4;
        const float4 m = *reinterpret_cast<const float4*>(row + d);
#pragma unroll
        for (int c = 0; c < 3; ++c) {
            const float4 w1 = *reinterpret_cast<const float4*>(W + c * 4096 + d);
            const float4 w2 = *reinterpret_cast<const float4*>(W + c * 4096 + 1024 + d);
            s[c]     += m.x * w1.x + m.y * w1.y + m.z * w1.z + m.w * w1.w;
            s[3 + c] += m.x * w2.x + m.y * w2.y + m.z * w2.z + m.w * w2.w;
        }
    }
#pragma unroll
    for (int off = 32; off; off >>= 1)
#pragma unroll
        for (int t = 0; t < 6; ++t)
            s[t] += __shfl_xor(s[t], off, 64);

    if (lane < 3) {
        P12[wave * 3 + lane]        = s[lane];      // P1 (W1 part)
        P12[3072 + wave * 3 + lane] = s[3 + lane];  // P2 (W2 part)
    }
}

// ---------------------------------------------------------------------------
// Kernel B: one block per (b, i) pair; 4 waves, each wave handles 16 j's.
// Lane owns d-set {k*256 + lane*4 + e : k=0..3, e=0..3} (16 elements).
// Registers hold mi, W3[c], W4[c] for the lane's d-set.
//   out[b,i,j,c] = P1[b,j,c] + P2[b,i,c]
//                + sum_d |mi-mj| * W3[c,d] + sum_d mi*mj * W4[c,d]
// ---------------------------------------------------------------------------
__global__ __launch_bounds__(256) void pair_kernel(
    const float* __restrict__ Mp, const float* __restrict__ W,
    const float* __restrict__ P12, float* __restrict__ out)
{
    const int b   = blockIdx.x >> 6;
    const int i   = blockIdx.x & 63;
    const int wid = threadIdx.x >> 6;   // 0..3
    const int lane = threadIdx.x & 63;

    const float* batch = Mp + (size_t)b * KK * D_MODEL;
    const float* rowi  = batch + i * D_MODEL;

    float4 mi[4], w3[3][4], w4[3][4];
#pragma unroll
    for (int k = 0; k < 4; ++k) {
        const int d = k * 256 + lane * 4;
        mi[k] = *reinterpret_cast<const float4*>(rowi + d);
#pragma unroll
        for (int c = 0; c < 3; ++c) {
            w3[c][k] = *reinterpret_cast<const float4*>(W + c * 4096 + 2048 + d);
            w4[c][k] = *reinterpret_cast<const float4*>(W + c * 4096 + 3072 + d);
        }
    }

    const float p2c0 = P12[3072 + (b * 64 + i) * 3 + 0];
    const float p2c1 = P12[3072 + (b * 64 + i) * 3 + 1];
    const float p2c2 = P12[3072 + (b * 64 + i) * 3 + 2];

#pragma unroll 1
    for (int jj = 0; jj < 16; ++jj) {
        const int j = wid * 16 + jj;
        const float* rowj = batch + j * D_MODEL;

        float s3[3] = {0.f, 0.f, 0.f};
        float s4[3] = {0.f, 0.f, 0.f};
#pragma unroll
        for (int k = 0; k < 4; ++k) {
            const float4 mj = *reinterpret_cast<const float4*>(rowj + k * 256 + lane * 4);
#define TERM(E)                                                                \
            {                                                                  \
                const float dabs = fabsf(mi[k].E - mj.E);                      \
                const float prod = mi[k].E * mj.E;                             \
                s3[0] += dabs * w3[0][k].E;                                    \
                s3[1] += dabs * w3[1][k].E;                                    \
                s3[2] += dabs * w3[2][k].E;                                    \
                s4[0] += prod * w4[0][k].E;                                    \
                s4[1] += prod * w4[1][k].E;                                    \
                s4[2] += prod * w4[2][k].E;                                    \
            }
            TERM(x) TERM(y) TERM(z) TERM(w)
#undef TERM
        }

#pragma unroll
        for (int off = 32; off; off >>= 1) {
#pragma unroll
            for (int t = 0; t < 3; ++t) {
                s3[t] += __shfl_xor(s3[t], off, 64);
                s4[t] += __shfl_xor(s4[t], off, 64);
            }
        }

        if (lane < 3) {
            const int c = lane;
            out[(((size_t)b * 64 + i) * 64 + j) * 3 + c] =
                P12[(b * 64 + j) * 3 + c] + ((c == 0) ? p2c0 : (c == 1) ? p2c1 : p2c2)
                + s3[c] + s4[c];
        }
    }
}

extern "C" void kernel_launch(void* const* d_in, const int* in_sizes, int n_in,
                              void* d_out, int out_size, void* d_ws, size_t ws_size,
                              hipStream_t stream)
{
    const float* Mp = (const float*)d_in[0];   // (16, 64, 1024) f32
    // d_in[1] = mask_p: unused by the reference (all-ones mask, never applied)
    const float* W  = (const float*)d_in[2];   // (3, 4096) f32
    float* out = (float*)d_out;                // (16, 64, 64, 3) f32
    float* P12 = (float*)d_ws;                 // 6144 floats scratch

    // Kernel A: 1024 waves = 256 blocks x 256 threads
    precompute_rows<<<256, 256, 0, stream>>>(Mp, W, P12);
    // Kernel B: one block per (b, i) pair
    pair_kernel<<<BSZ * KK, 256, 0, stream>>>(Mp, W, P12, out);
}

// Round 2
// 81.620 us; speedup vs baseline: 1.2414x; 1.2414x over previous
//
#include <hip/hip_runtime.h>

#define D_MODEL 1024
#define KK 64
#define BSZ 16

// ---------------------------------------------------------------------------
// Kernel A: one block (4 waves) per row r in [0, 1024). Wave w handles
// d-chunk [w*256, w*256+256); partial sums combined through LDS.
//   P1[r][c] = sum_d Mp[r,d]*W[c,d]        -> P12[r*3+c]
//   P2[r][c] = sum_d Mp[r,d]*W[c,1024+d]   -> P12[3072 + r*3+c]
// ---------------------------------------------------------------------------
__global__ __launch_bounds__(256) void precompute_rows(
    const float* __restrict__ Mp, const float* __restrict__ W,
    float* __restrict__ P12)
{
    const int row  = blockIdx.x;           // 0..1023
    const int wid  = threadIdx.x >> 6;     // 0..3
    const int lane = threadIdx.x & 63;
    const int d    = wid * 256 + lane * 4;

    const float4 m = *reinterpret_cast<const float4*>(Mp + (size_t)row * D_MODEL + d);
    float s[6];
#pragma unroll
    for (int c = 0; c < 3; ++c) {
        const float4 w1 = *reinterpret_cast<const float4*>(W + c * 4096 + d);
        const float4 w2 = *reinterpret_cast<const float4*>(W + c * 4096 + 1024 + d);
        s[c]     = m.x * w1.x + m.y * w1.y + m.z * w1.z + m.w * w1.w;
        s[3 + c] = m.x * w2.x + m.y * w2.y + m.z * w2.z + m.w * w2.w;
    }
#pragma unroll
    for (int off = 32; off; off >>= 1)
#pragma unroll
        for (int t = 0; t < 6; ++t)
            s[t] += __shfl_xor(s[t], off, 64);

    __shared__ float part[4][6];
    if (lane == 0) {
#pragma unroll
        for (int t = 0; t < 6; ++t) part[wid][t] = s[t];
    }
    __syncthreads();
    if (threadIdx.x < 6) {
        const int t = threadIdx.x;
        const float v = part[0][t] + part[1][t] + part[2][t] + part[3][t];
        if (t < 3) P12[row * 3 + t]              = v;
        else       P12[3072 + row * 3 + (t - 3)] = v;
    }
}

// ---------------------------------------------------------------------------
// Kernel B: upper-triangle pairs only (2080 per batch), write (i,j) and (j,i).
// Grid (16, 65): x = batch (fast dim -> all of a batch's blocks share an XCD
// since 16 % 8 == 0), y = slot. Block = 4 waves; wave handles 8 consecutive
// linear pair indices p = slot*32 + wid*8 + t.
// Lane owns d-set {k*256 + lane*4 + e}. W3/W4 pinned in VGPRs via opaque asm.
// ---------------------------------------------------------------------------
__device__ __forceinline__ int tri_start(int i) { return (i * (129 - i)) >> 1; }

__global__ __launch_bounds__(256, 2) void pair_kernel(
    const float* __restrict__ Mp, const float* __restrict__ W,
    const float* __restrict__ P12, float* __restrict__ out)
{
    const int b    = blockIdx.x;          // 0..15
    const int slot = blockIdx.y;          // 0..64
    const int wid  = threadIdx.x >> 6;    // 0..3
    const int lane = threadIdx.x & 63;

    const float* batch = Mp + (size_t)b * KK * D_MODEL;
    float*       outb  = out + (size_t)b * KK * KK * 3;
    const float* P1    = P12 + b * KK * 3;
    const float* P2    = P12 + 3072 + b * KK * 3;

    // Load W3/W4 fragments once and pin them in registers (prevents the
    // compiler from rematerializing these 24 loads inside the pair loop,
    // which is what made the previous version latency-bound at VGPR=84).
    float4 w3[3][4], w4[3][4];
#pragma unroll
    for (int k = 0; k < 4; ++k) {
        const int d = k * 256 + lane * 4;
#pragma unroll
        for (int c = 0; c < 3; ++c) {
            w3[c][k] = *reinterpret_cast<const float4*>(W + c * 4096 + 2048 + d);
            w4[c][k] = *reinterpret_cast<const float4*>(W + c * 4096 + 3072 + d);
        }
    }
#define KEEP4(f) asm volatile("" : "+v"(f.x), "+v"(f.y), "+v"(f.z), "+v"(f.w))
#pragma unroll
    for (int c = 0; c < 3; ++c)
#pragma unroll
        for (int k = 0; k < 4; ++k) { KEEP4(w3[c][k]); KEEP4(w4[c][k]); }
#undef KEEP4

    // Decode first (i, j) of this wave's 8-pair run (scalar, wave-uniform).
    const int p0 = slot * 32 + wid * 8;
    int i = (int)((129.0f - sqrtf(16641.0f - 8.0f * (float)p0)) * 0.5f);
    if (i > 63) i = 63;
    if (i < 0)  i = 0;
    while (tri_start(i + 1) <= p0) ++i;
    while (tri_start(i) > p0) --i;
    int j = i + (p0 - tri_start(i));

    float4 mi[4];
#pragma unroll
    for (int k = 0; k < 4; ++k)
        mi[k] = *reinterpret_cast<const float4*>(batch + i * D_MODEL + k * 256 + lane * 4);

#pragma unroll 2
    for (int t = 0; t < 8; ++t) {
        const float* rowj = batch + j * D_MODEL;
        float sc0 = 0.f, sc1 = 0.f, sc2 = 0.f;  // s3[c] + s4[c] combined
#pragma unroll
        for (int k = 0; k < 4; ++k) {
            const float4 mj = *reinterpret_cast<const float4*>(rowj + k * 256 + lane * 4);
#define TERM(E)                                                      \
            {                                                        \
                const float dabs = fabsf(mi[k].E - mj.E);            \
                const float prod = mi[k].E * mj.E;                   \
                sc0 += dabs * w3[0][k].E;  sc0 += prod * w4[0][k].E; \
                sc1 += dabs * w3[1][k].E;  sc1 += prod * w4[1][k].E; \
                sc2 += dabs * w3[2][k].E;  sc2 += prod * w4[2][k].E; \
            }
            TERM(x) TERM(y) TERM(z) TERM(w)
#undef TERM
        }

#pragma unroll
        for (int off = 32; off; off >>= 1) {
            sc0 += __shfl_xor(sc0, off, 64);
            sc1 += __shfl_xor(sc1, off, 64);
            sc2 += __shfl_xor(sc2, off, 64);
        }

        if (lane < 3) {
            const int c = lane;
            const float sc = (c == 0) ? sc0 : (c == 1) ? sc1 : sc2;
            outb[(i * KK + j) * 3 + c] = P1[j * 3 + c] + P2[i * 3 + c] + sc;
            outb[(j * KK + i) * 3 + c] = P1[i * 3 + c] + P2[j * 3 + c] + sc;
        }

        // advance to next pair in the triangle (wave-uniform scalar control)
        ++j;
        if (j == KK) {
            ++i;
            if (i < KK) {
                j = i;
#pragma unroll
                for (int k = 0; k < 4; ++k)
                    mi[k] = *reinterpret_cast<const float4*>(batch + i * D_MODEL + k * 256 + lane * 4);
            }
        }
    }
}

extern "C" void kernel_launch(void* const* d_in, const int* in_sizes, int n_in,
                              void* d_out, int out_size, void* d_ws, size_t ws_size,
                              hipStream_t stream)
{
    const float* Mp = (const float*)d_in[0];   // (16, 64, 1024) f32
    // d_in[1] = mask_p: unused by the reference (all-ones, never applied)
    const float* W  = (const float*)d_in[2];   // (3, 4096) f32
    float* out = (float*)d_out;                // (16, 64, 64, 3) f32
    float* P12 = (float*)d_ws;                 // 6144 floats scratch

    precompute_rows<<<1024, 256, 0, stream>>>(Mp, W, P12);
    pair_kernel<<<dim3(BSZ, 65), 256, 0, stream>>>(Mp, W, P12, out);
}